// Round 19
// baseline (1431.609 us; speedup 1.0000x reference)
//
#include <hip/hip_runtime.h>
#include <cstdint>
#include <cstddef>

constexpr int LSEQ = 1000;   // sequence length
constexpr int NB   = 128;    // batch
constexpr int CINP = 12;     // input channels
constexpr int HID  = 128;    // lstm hidden
constexpr int NGATE = 4 * HID;  // 512
constexpr int DMOD = 128;    // d_model
constexpr int DINN = 256;    // d_inner
constexpr int NCL  = 5;

typedef unsigned short ushort_t;
typedef _Float16 half2_t __attribute__((ext_vector_type(2)));
typedef _Float16 half8_t __attribute__((ext_vector_type(8)));
typedef float f32x4 __attribute__((ext_vector_type(4)));

__device__ __forceinline__ float bf2f(ushort_t u) {
  uint32_t b = ((uint32_t)u) << 16;
  float f; __builtin_memcpy(&f, &b, 4); return f;
}
__device__ __forceinline__ ushort_t f2bf(float f) {
  uint32_t b; __builtin_memcpy(&b, &f, 4);
  uint32_t r = (b + 0x7fffu + ((b >> 16) & 1u)) >> 16;
  return (ushort_t)r;
}
__device__ __forceinline__ half2_t u2h2(uint32_t v) {
  half2_t h; __builtin_memcpy(&h, &v, 4); return h;
}
__device__ __forceinline__ uint32_t h22u(half2_t h) {
  uint32_t v; __builtin_memcpy(&v, &h, 4); return v;
}
__device__ __forceinline__ half8_t u4_to_h8(uint4 v) {
  half8_t h; __builtin_memcpy(&h, &v, 16); return h;
}
// two bf16 packed in u32 -> two f16 packed in u32
__device__ __forceinline__ uint32_t bfpair_to_h2(uint32_t v) {
  half2_t h;
  h.x = (_Float16)bf2f((ushort_t)(v & 0xffff));
  h.y = (_Float16)bf2f((ushort_t)(v >> 16));
  return h22u(h);
}

#if __has_builtin(__builtin_amdgcn_fdot2)
__device__ __forceinline__ float FDOT2(half2_t a, half2_t b, float c) {
  return __builtin_amdgcn_fdot2(a, b, c, false);
}
#else
__device__ __forceinline__ float FDOT2(half2_t a, half2_t b, float c) {
  return c + (float)a.x * (float)b.x + (float)a.y * (float)b.y;
}
#endif

// LDS-only barrier: drains lgkmcnt but NOT vmcnt (global stores keep flowing).
__device__ __forceinline__ void bar_lgkm() {
  asm volatile("s_waitcnt lgkmcnt(0)\n\ts_barrier" ::: "memory");
}

// ---------------------------------------------------------------------------
// K0: fold input_proj into in_proj; emit Weff PRE-PACKED as f16 pairs.
__global__ __launch_bounds__(256) void k0_weff(
    const float* __restrict__ ipw, const float* __restrict__ Wp,
    const float* __restrict__ bp, uint32_t* __restrict__ Weffh,
    float* __restrict__ beff) {
  int idx = blockIdx.x * 256 + threadIdx.x;   // grid 128 blocks -> 32768
  if (idx < NGATE * 64) {
    int e = idx >> 6, j = idx & 63;
    float a0 = 0.f, a1 = 0.f;
    for (int d = 0; d < DMOD; ++d) {
      float w = ipw[e * DMOD + d];
      a0 += w * Wp[d * HID + 2 * j];
      a1 += w * Wp[d * HID + 2 * j + 1];
    }
    half2_t h; h.x = (_Float16)a0; h.y = (_Float16)a1;
    Weffh[idx] = h22u(h);
  }
  if (idx < NGATE) {
    float acc = 0.f;
    for (int d = 0; d < DMOD; ++d) acc += ipw[idx * DMOD + d] * bp[d];
    beff[idx] = acc;
  }
}

// ---------------------------------------------------------------------------
// K1: LSTM "split-gate" (FROZEN; best measured: 748 us).
__global__ __launch_bounds__(256, 1) void k1_lstm(
    const float* __restrict__ x, const float* __restrict__ W_ih,
    const float* __restrict__ W_hh, const float* __restrict__ b_ih,
    const float* __restrict__ b_hh, ushort_t* __restrict__ hout) {
  __shared__ __align__(16) float x_sh[LSEQ * CINP];      // 48 KB
  __shared__ __align__(16) ushort_t h_sh[HID];           // f16 bits
  __shared__ float tg_sh[HID];                           // tanh(g) from half1
  __shared__ float so_sh[HID];                           // sig(o)  from half1
  const int t = threadIdx.x;          // 0..255
  const int u = t & 127;              // unit
  const int half = t >> 7;            // 0: rows {u,u+128}; 1: {u+256,u+384}
  const int rA = u + half * 256;      // i or g
  const int rB = rA + 128;            // f or o
  const int b = blockIdx.x;

  const float4* xg4 = reinterpret_cast<const float4*>(x + (size_t)b * LSEQ * CINP);
  float4* xs4 = reinterpret_cast<float4*>(x_sh);
  for (int i = t; i < LSEQ * CINP / 4; i += 256) xs4[i] = xg4[i];

  half2_t wa2[64], wb2[64];
  {
    const float4* wa4 = reinterpret_cast<const float4*>(W_hh) + rA * (HID / 4);
    const float4* wb4 = reinterpret_cast<const float4*>(W_hh) + rB * (HID / 4);
#pragma unroll
    for (int k = 0; k < HID / 4; ++k) {
      float4 v = wa4[k];
      half2_t a; a.x = (_Float16)v.x; a.y = (_Float16)v.y;
      half2_t c; c.x = (_Float16)v.z; c.y = (_Float16)v.w;
      wa2[2 * k] = a; wa2[2 * k + 1] = c;
      float4 w = wb4[k];
      half2_t d; d.x = (_Float16)w.x; d.y = (_Float16)w.y;
      half2_t e; e.x = (_Float16)w.z; e.y = (_Float16)w.w;
      wb2[2 * k] = d; wb2[2 * k + 1] = e;
    }
  }
  float wia[CINP], wib[CINP];
#pragma unroll
  for (int c = 0; c < CINP; ++c) {
    wia[c] = W_ih[rA * CINP + c];
    wib[c] = W_ih[rB * CINP + c];
  }
  const float biasA = b_ih[rA] + b_hh[rA];
  const float biasB = b_ih[rB] + b_hh[rB];

  float cstate = 0.f;
  if (t < HID) h_sh[t] = 0;
  __syncthreads();

  for (int l = 0; l < LSEQ; ++l) {
    const float* xr = &x_sh[l * CINP];
    float pa0 = biasA, pa1 = 0.f, pa2 = 0.f, pa3 = 0.f;
    float pb0 = biasB, pb1 = 0.f, pb2 = 0.f, pb3 = 0.f;
#pragma unroll
    for (int c = 0; c < CINP; c += 4) {
      float x0 = xr[c], x1 = xr[c + 1], x2 = xr[c + 2], x3 = xr[c + 3];
      pa0 += x0 * wia[c];     pa1 += x1 * wia[c + 1];
      pa2 += x2 * wia[c + 2]; pa3 += x3 * wia[c + 3];
      pb0 += x0 * wib[c];     pb1 += x1 * wib[c + 1];
      pb2 += x2 * wib[c + 2]; pb3 += x3 * wib[c + 3];
    }
    const uint4* h4 = reinterpret_cast<const uint4*>(h_sh);
#pragma unroll
    for (int kk = 0; kk < 16; ++kk) {
      uint4 hv = h4[kk];
      half2_t h0 = u2h2(hv.x), h1 = u2h2(hv.y), h2 = u2h2(hv.z), h3 = u2h2(hv.w);
      pa0 = FDOT2(h0, wa2[4 * kk],     pa0);
      pa1 = FDOT2(h1, wa2[4 * kk + 1], pa1);
      pa2 = FDOT2(h2, wa2[4 * kk + 2], pa2);
      pa3 = FDOT2(h3, wa2[4 * kk + 3], pa3);
      pb0 = FDOT2(h0, wb2[4 * kk],     pb0);
      pb1 = FDOT2(h1, wb2[4 * kk + 1], pb1);
      pb2 = FDOT2(h2, wb2[4 * kk + 2], pb2);
      pb3 = FDOT2(h3, wb2[4 * kk + 3], pb3);
    }
    float gA = (pa0 + pa1) + (pa2 + pa3);
    float gB = (pb0 + pb1) + (pb2 + pb3);

    float si = 0.f, sf = 0.f;
    if (half) {
      float tg = 1.f - 2.f / (__expf(2.f * gA) + 1.f);
      float so = 1.f / (1.f + __expf(-gB));
      tg_sh[u] = tg;
      so_sh[u] = so;
    } else {
      si = 1.f / (1.f + __expf(-gA));
      sf = 1.f / (1.f + __expf(-gB));
    }
    bar_lgkm();
    if (!half) {
      cstate = sf * cstate + si * tg_sh[u];
      float th = 1.f - 2.f / (__expf(2.f * cstate) + 1.f);
      float hv = so_sh[u] * th;
      _Float16 hh = (_Float16)hv;
      ushort_t hb; __builtin_memcpy(&hb, &hh, 2);
      h_sh[u] = hb;
      hout[((size_t)b * LSEQ + l) * HID + u] = f2bf(hv);
    }
    bar_lgkm();
  }
}

// ---------------------------------------------------------------------------
// K2f: xz = h @ Weff.T + beff via MFMA (16x16x32 f16), FUSED with causal
//      conv+silu. Grid TRANSPOSED (n0 = blockIdx.x): the 8 column-blocks of
//      one row-tile are dispatch-adjacent -> hbuf rows hit L2/L3 while hot.
__global__ __launch_bounds__(256) void k2f(
    const ushort_t* __restrict__ hbuf, const uint32_t* __restrict__ Weffh,
    const float* __restrict__ beff, const float* __restrict__ cw,
    const float* __restrict__ cb, ushort_t* __restrict__ xs,
    ushort_t* __restrict__ sz) {
  constexpr int S = 66;                        // u32 stride per 64-pair row
  __shared__ __align__(16) uint32_t smem[2 * 64 * S];   // 33,792 B
  uint32_t* As = smem;
  uint32_t* Bs = smem + 64 * S;
  const int tid = threadIdx.x;
  const size_t m0 = (size_t)blockIdx.y * 64;
  const int n0 = blockIdx.x * 64;

  const uint4* h4g = reinterpret_cast<const uint4*>(hbuf);
  for (int i = tid; i < 64 * 16; i += 256) {
    int row = i >> 4, c = i & 15;
    uint4 v = h4g[(m0 + row) * 16 + c];
    uint32_t* p = &As[row * S + c * 4];
    p[0] = bfpair_to_h2(v.x); p[1] = bfpair_to_h2(v.y);
    p[2] = bfpair_to_h2(v.z); p[3] = bfpair_to_h2(v.w);
  }
  const uint4* w4g = reinterpret_cast<const uint4*>(Weffh);
  for (int i = tid; i < 64 * 16; i += 256) {
    int row = i >> 4, c = i & 15;
    uint4 v = w4g[(size_t)(n0 + row) * 16 + c];
    uint32_t* p = &Bs[row * S + c * 4];
    p[0] = v.x; p[1] = v.y; p[2] = v.z; p[3] = v.w;
  }
  __syncthreads();

  const int w  = tid >> 6;        // wave id -> row-tile
  const int ln = tid & 63;
  const int mr = ln & 15;         // M (A) / N (B) index within tile
  const int g4 = (ln >> 4) * 4;   // kpair offset of this lane group

  uint4 af[4];
#pragma unroll
  for (int kb = 0; kb < 4; ++kb)
    af[kb] = *reinterpret_cast<const uint4*>(&As[(w * 16 + mr) * S + kb * 16 + g4]);

  f32x4 acc[4];
#pragma unroll
  for (int tn = 0; tn < 4; ++tn) {
    f32x4 a = {0.f, 0.f, 0.f, 0.f};
#pragma unroll
    for (int kb = 0; kb < 4; ++kb) {
      uint4 bf = *reinterpret_cast<const uint4*>(&Bs[(tn * 16 + mr) * S + kb * 16 + g4]);
      a = __builtin_amdgcn_mfma_f32_16x16x32_f16(u4_to_h8(af[kb]), u4_to_h8(bf), a, 0, 0, 0);
    }
    acc[tn] = a;
  }

  const int rbase = w * 16 + (ln >> 4) * 4;   // row within 64-row tile

  if (n0 >= 256) {
    // z path: silu -> sz
#pragma unroll
    for (int tn = 0; tn < 4; ++tn) {
      int c = n0 + tn * 16 + mr;
      float bev = beff[c];
#pragma unroll
      for (int r = 0; r < 4; ++r) {
        size_t row = m0 + rbase + r;
        float v = acc[tn][r] + bev;
        sz[row * 256 + (c - 256)] = f2bf(v / (1.f + __expf(-v)));
      }
    }
    return;
  }

  // xi path: 3-row halo xz (rows m0-3..m0-1), masked at batch starts
  float haloval = 0.f;
  const int hc = tid & 63;
  if (tid < 192) {
    int hr = tid >> 6;
    long hrow = (long)m0 - 3 + hr;
    if (hrow < 0) hrow = 0;        // values masked by l-check below
    const uint4* hg = reinterpret_cast<const uint4*>(hbuf + (size_t)hrow * 128);
    const uint32_t* brow = &Bs[hc * S];
    float a0 = beff[n0 + hc], a1 = 0.f, a2 = 0.f, a3 = 0.f;
#pragma unroll
    for (int k = 0; k < 16; ++k) {
      uint4 hv = hg[k];
      a0 = FDOT2(u2h2(bfpair_to_h2(hv.x)), u2h2(brow[4 * k]),     a0);
      a1 = FDOT2(u2h2(bfpair_to_h2(hv.y)), u2h2(brow[4 * k + 1]), a1);
      a2 = FDOT2(u2h2(bfpair_to_h2(hv.z)), u2h2(brow[4 * k + 2]), a2);
      a3 = FDOT2(u2h2(bfpair_to_h2(hv.w)), u2h2(brow[4 * k + 3]), a3);
    }
    haloval = (a0 + a1) + (a2 + a3);
  }
  __syncthreads();   // As/Bs reads complete -> safe to overlay

  float* X = reinterpret_cast<float*>(smem);   // [67][68] fp32 xz tile
#pragma unroll
  for (int tn = 0; tn < 4; ++tn) {
    int c = tn * 16 + mr;
    float bev = beff[n0 + c];
#pragma unroll
    for (int r = 0; r < 4; ++r) {
      X[(rbase + r + 3) * 68 + c] = acc[tn][r] + bev;
    }
  }
  if (tid < 192) X[(tid >> 6) * 68 + hc] = haloval;
  __syncthreads();

  // conv (l-masked) + silu -> xs  (re-reads X with the ty/tx mapping)
  const int tx = tid & 15, ty = tid >> 4;
  const int col = n0 + tx * 4;
  float cw0[4], cw1[4], cw2[4], cw3[4], cbv[4];
#pragma unroll
  for (int j = 0; j < 4; ++j) {
    int d = col + j;
    cw0[j] = cw[d * 4]; cw1[j] = cw[d * 4 + 1];
    cw2[j] = cw[d * 4 + 2]; cw3[j] = cw[d * 4 + 3];
    cbv[j] = cb[d];
  }
#pragma unroll
  for (int i = 0; i < 4; ++i) {
    int r = ty * 4 + i;
    size_t m = m0 + r;
    int l = (int)(m % LSEQ);
    const float* xr3 = &X[(r + 3) * 68 + tx * 4];  // current row
    ushort_t ov[4];
#pragma unroll
    for (int j = 0; j < 4; ++j) {
      float o0 = cbv[j];
      o0 += cw3[j] * xr3[j];
      if (l >= 1) o0 += cw2[j] * xr3[j - 68];
      if (l >= 2) o0 += cw1[j] * xr3[j - 136];
      if (l >= 3) o0 += cw0[j] * xr3[j - 204];
      ov[j] = f2bf(o0 / (1.f + __expf(-o0)));
    }
    ushort4 o; o.x = ov[0]; o.y = ov[1]; o.z = ov[2]; o.w = ov[3];
    *reinterpret_cast<ushort4*>(&xs[m * 256 + col]) = o;
  }
}

// ---------------------------------------------------------------------------
// K4: x_dbl = xs @ x_proj_w.T via MFMA (verified R18).
__global__ __launch_bounds__(256) void k4_xdbl(
    const ushort_t* __restrict__ xs, const float* __restrict__ xpw,
    float* __restrict__ dtg, float* __restrict__ bc) {
  constexpr int S = 130;                       // u32 stride per 128-pair row
  __shared__ __align__(16) uint32_t xsh[64 * S];   // 33.3 KB
  __shared__ __align__(16) uint32_t wsh[48 * S];   // 25.0 KB
  const int tid = threadIdx.x;
  const size_t r0 = (size_t)blockIdx.x * 64;

  const uint4* x4g = reinterpret_cast<const uint4*>(xs);
  for (int i = tid; i < 64 * 32; i += 256) {
    int row = i >> 5, c = i & 31;
    uint4 v = x4g[(r0 + row) * 32 + c];
    uint32_t* p = &xsh[row * S + c * 4];
    p[0] = bfpair_to_h2(v.x); p[1] = bfpair_to_h2(v.y);
    p[2] = bfpair_to_h2(v.z); p[3] = bfpair_to_h2(v.w);
  }
  for (int i = tid; i < 40 * 128; i += 256) {
    int c = i >> 7, kk = i & 127;
    half2_t h;
    h.x = (_Float16)xpw[c * 256 + 2 * kk];
    h.y = (_Float16)xpw[c * 256 + 2 * kk + 1];
    wsh[c * S + kk] = h22u(h);
  }
  for (int i = tid; i < 8 * 128; i += 256) {
    int c = 40 + (i >> 7), kk = i & 127;
    wsh[c * S + kk] = 0u;
  }
  __syncthreads();

  const int w  = tid >> 6;        // wave id -> 16-row tile
  const int ln = tid & 63;
  const int mr = ln & 15;
  const int g4 = (ln >> 4) * 4;

  uint4 af[8];
#pragma unroll
  for (int kb = 0; kb < 8; ++kb)
    af[kb] = *reinterpret_cast<const uint4*>(&xsh[(w * 16 + mr) * S + kb * 16 + g4]);

  f32x4 acc[3];
#pragma unroll
  for (int tn = 0; tn < 3; ++tn) {
    f32x4 a = {0.f, 0.f, 0.f, 0.f};
#pragma unroll
    for (int kb = 0; kb < 8; ++kb) {
      uint4 bf = *reinterpret_cast<const uint4*>(&wsh[(tn * 16 + mr) * S + kb * 16 + g4]);
      a = __builtin_amdgcn_mfma_f32_16x16x32_f16(u4_to_h8(af[kb]), u4_to_h8(bf), a, 0, 0, 0);
    }
    acc[tn] = a;
  }

  const int rbase = w * 16 + (ln >> 4) * 4;
#pragma unroll
  for (int tn = 0; tn < 3; ++tn) {
    int c = tn * 16 + mr;
#pragma unroll
    for (int r = 0; r < 4; ++r) {
      size_t row = r0 + rbase + r;
      float v = acc[tn][r];
      if (c < 8) dtg[row * 8 + c] = v;
      else if (c < 40) bc[row * 32 + (c - 8)] = v;
    }
  }
}

// ---------------------------------------------------------------------------
// K5: selective scan, 4 threads per (b,d) with 4 states each. Per-wave fixed
//     overhead (dt-FMA + softplus, SIMT-free across a group's lanes) is now
//     amortized over 16 groups/wave instead of 8 (~0.6x wave-ops/group).
//     Software prefetch of l+1; reduction (2 shfl) hoisted out of the loop.
__global__ __launch_bounds__(256) void k5_scan(
    const float* __restrict__ dtg, const ushort_t* __restrict__ xs,
    const ushort_t* __restrict__ sz, const float* __restrict__ bc,
    const float* __restrict__ A_log, const float* __restrict__ Dv,
    const float* __restrict__ dtw, const float* __restrict__ dtb,
    float* __restrict__ ysum) {
  const int b  = blockIdx.x >> 2;
  const int d  = ((blockIdx.x & 3) << 6) + (threadIdx.x >> 2);  // 0..255
  const int sg = threadIdx.x & 3;                                // 4 states each

  float Aa[4];
#pragma unroll
  for (int s = 0; s < 4; ++s) Aa[s] = -__expf(A_log[d * 16 + sg * 4 + s]);
  float w8[8];
#pragma unroll
  for (int r = 0; r < 8; ++r) w8[r] = dtw[d * 8 + r];
  const float db = dtb[d];
  const float DD = Dv[d];

  float h0 = 0.f, h1 = 0.f, h2 = 0.f, h3 = 0.f;
  float acc = 0.f, accD = 0.f;
  const size_t base = (size_t)b * LSEQ;

  float4 dta_c = *reinterpret_cast<const float4*>(&dtg[base * 8]);
  float4 dtb_c = *reinterpret_cast<const float4*>(&dtg[base * 8 + 4]);
  float  xv_c  = bf2f(xs[base * 256 + d]);
  float  zv_c  = bf2f(sz[base * 256 + d]);
  float4 bv_c  = *reinterpret_cast<const float4*>(&bc[base * 32 + sg * 4]);
  float4 cv_c  = *reinterpret_cast<const float4*>(&bc[base * 32 + 16 + sg * 4]);

  for (int l = 0; l < LSEQ; ++l) {
    const size_t nrow = base + ((l + 1 < LSEQ) ? (l + 1) : l);
    float4 dta_n = *reinterpret_cast<const float4*>(&dtg[nrow * 8]);
    float4 dtb_n = *reinterpret_cast<const float4*>(&dtg[nrow * 8 + 4]);
    float  xv_n  = bf2f(xs[nrow * 256 + d]);
    float  zv_n  = bf2f(sz[nrow * 256 + d]);
    float4 bv_n  = *reinterpret_cast<const float4*>(&bc[nrow * 32 + sg * 4]);
    float4 cv_n  = *reinterpret_cast<const float4*>(&bc[nrow * 32 + 16 + sg * 4]);

    float a = db + dta_c.x * w8[0] + dta_c.y * w8[1] + dta_c.z * w8[2] + dta_c.w * w8[3]
                 + dtb_c.x * w8[4] + dtb_c.y * w8[5] + dtb_c.z * w8[6] + dtb_c.w * w8[7];
    float dl = (a > 20.f) ? a : __logf(1.f + __expf(a));
    float dx = dl * xv_c;
    h0 = __expf(dl * Aa[0]) * h0 + dx * bv_c.x;
    h1 = __expf(dl * Aa[1]) * h1 + dx * bv_c.y;
    h2 = __expf(dl * Aa[2]) * h2 + dx * bv_c.z;
    h3 = __expf(dl * Aa[3]) * h3 + dx * bv_c.w;
    acc += (h0 * cv_c.x + h1 * cv_c.y + h2 * cv_c.z + h3 * cv_c.w) * zv_c;
    accD += xv_c * zv_c;

    dta_c = dta_n; dtb_c = dtb_n;
    xv_c = xv_n; zv_c = zv_n; bv_c = bv_n; cv_c = cv_n;
  }
  if (sg == 0) acc += DD * accD;
  acc += __shfl_xor(acc, 1);
  acc += __shfl_xor(acc, 2);
  if (sg == 0) ysum[b * 256 + d] = acc;
}

// ---------------------------------------------------------------------------
// K6: head. pooled = ysum@opw.T/L ; fc1+relu ; fc2.
__global__ __launch_bounds__(128) void k6_head(
    const float* __restrict__ ysum, const float* __restrict__ opw,
    const float* __restrict__ fc1w, const float* __restrict__ fc1b,
    const float* __restrict__ fc2w, const float* __restrict__ fc2b,
    float* __restrict__ out) {
  __shared__ float ys[256], pool[128], fcs[128];
  const int b = blockIdx.x, t = threadIdx.x;
  for (int i = t; i < 256; i += 128) ys[i] = ysum[b * 256 + i];
  __syncthreads();
  float a = 0.f;
  for (int e = 0; e < 256; ++e) a += opw[t * 256 + e] * ys[e];
  pool[t] = a * (1.0f / (float)LSEQ);
  __syncthreads();
  float a1 = fc1b[t];
  for (int d2 = 0; d2 < 128; ++d2) a1 += fc1w[t * 128 + d2] * pool[d2];
  fcs[t] = fmaxf(a1, 0.f);
  __syncthreads();
  if (t < NCL) {
    float o = fc2b[t];
    for (int f = 0; f < 128; ++f) o += fc2w[t * 128 + f] * fcs[f];
    out[b * NCL + t] = o;
  }
}

// ---------------------------------------------------------------------------
extern "C" void kernel_launch(void* const* d_in, const int* in_sizes, int n_in,
                              void* d_out, int out_size, void* d_ws, size_t ws_size,
                              hipStream_t stream) {
  const float* x     = (const float*)d_in[0];
  const float* W_ih  = (const float*)d_in[1];
  const float* W_hh  = (const float*)d_in[2];
  const float* b_ih  = (const float*)d_in[3];
  const float* b_hh  = (const float*)d_in[4];
  const float* Wp    = (const float*)d_in[5];
  const float* bp    = (const float*)d_in[6];
  const float* ipw   = (const float*)d_in[7];
  const float* cw    = (const float*)d_in[8];
  const float* cb    = (const float*)d_in[9];
  const float* xpw   = (const float*)d_in[10];
  const float* dtw   = (const float*)d_in[11];
  const float* dtb   = (const float*)d_in[12];
  const float* A_log = (const float*)d_in[13];
  const float* Dv    = (const float*)d_in[14];
  const float* opw   = (const float*)d_in[15];
  const float* fc1w  = (const float*)d_in[16];
  const float* fc1b  = (const float*)d_in[17];
  const float* fc2w  = (const float*)d_in[18];
  const float* fc2b  = (const float*)d_in[19];
  float* out = (float*)d_out;

  const size_t A_WEFF = 131072;                          // packed f16 pairs
  const size_t A_BEFF = 4096, A_YSUM = 131072;
  const size_t A_HBUF = (size_t)NB * LSEQ * HID * 2;     // 32.77 MB
  const size_t A_XS   = (size_t)NB * LSEQ * DINN * 2;    // 65.54 MB
  const size_t A_SZ   = A_XS;                            // 65.54 MB
  const size_t A_DT   = (size_t)NB * LSEQ * 8 * 4;       // 4.10 MB
  const size_t A_BC   = (size_t)NB * LSEQ * 32 * 4;      // 16.38 MB
  const size_t FIXED_WIDE = A_WEFF + A_BEFF + A_YSUM + A_HBUF + A_XS + A_SZ + A_DT + A_BC;
  // FIXED_WIDE = 184.6 MB (no xi buffer)

  if (FIXED_WIDE <= ws_size) {
    char* p = (char*)d_ws;
    uint32_t* Weffh = (uint32_t*)p; p += A_WEFF;
    float*    beff = (float*)p;    p += A_BEFF;
    float*    ysum = (float*)p;    p += A_YSUM;
    ushort_t* hbuf = (ushort_t*)p; p += A_HBUF;
    ushort_t* xsb  = (ushort_t*)p; p += A_XS;
    ushort_t* szb  = (ushort_t*)p; p += A_SZ;
    float*    dtg  = (float*)p;    p += A_DT;
    float*    bcb  = (float*)p;    p += A_BC;

    const int rows = NB * LSEQ;      // 128000
    hipLaunchKernelGGL(k0_weff, dim3(128), dim3(256), 0, stream, ipw, Wp, bp, Weffh, beff);
    hipLaunchKernelGGL(k1_lstm, dim3(NB), dim3(256), 0, stream, x, W_ih, W_hh, b_ih, b_hh, hbuf);
    hipLaunchKernelGGL(k2f, dim3(8, rows / 64), dim3(256), 0, stream,
                       hbuf, Weffh, beff, cw, cb, xsb, szb);
    hipLaunchKernelGGL(k4_xdbl, dim3(rows / 64), dim3(256), 0, stream,
                       xsb, xpw, dtg, bcb);
    hipLaunchKernelGGL(k5_scan, dim3(NB * 4), dim3(256), 0, stream,
                       dtg, xsb, szb, bcb, A_log, Dv, dtw, dtb, ysum);
    hipLaunchKernelGGL(k6_head, dim3(NB), dim3(128), 0, stream,
                       ysum, opw, fc1w, fc1b, fc2w, fc2b, out);
    return;
  }

  // --- fallback: chunked over batches (same fused kernel; chunks start at
  //     batch boundaries so the conv l-masking stays correct) ---
  const size_t FIXED = A_WEFF + A_BEFF + A_YSUM + A_HBUF;
  const size_t PERB = (size_t)LSEQ * DINN * 2 * 2 + (size_t)LSEQ * 8 * 4 + (size_t)LSEQ * 32 * 4;
  int nb = 8;
  for (int c = 64; c >= 8; c >>= 1) {
    if (FIXED + (size_t)c * PERB <= ws_size) { nb = c; break; }
  }
  char* p = (char*)d_ws;
  uint32_t* Weffh = (uint32_t*)p; p += A_WEFF;
  float*    beff = (float*)p;    p += A_BEFF;
  float*    ysum = (float*)p;    p += A_YSUM;
  ushort_t* hbuf = (ushort_t*)p; p += A_HBUF;
  ushort_t* xsb  = (ushort_t*)p; p += (size_t)nb * LSEQ * DINN * 2;
  ushort_t* szb  = (ushort_t*)p; p += (size_t)nb * LSEQ * DINN * 2;
  float*    dtg  = (float*)p;    p += (size_t)nb * LSEQ * 8 * 4;
  float*    bcb  = (float*)p;

  hipLaunchKernelGGL(k0_weff, dim3(128), dim3(256), 0, stream, ipw, Wp, bp, Weffh, beff);
  hipLaunchKernelGGL(k1_lstm, dim3(NB), dim3(256), 0, stream, x, W_ih, W_hh, b_ih, b_hh, hbuf);
  for (int b0 = 0; b0 < NB; b0 += nb) {
    const int rows = nb * LSEQ;
    hipLaunchKernelGGL(k2f, dim3(8, rows / 64), dim3(256), 0, stream,
                       hbuf + (size_t)b0 * LSEQ * HID, Weffh, beff, cw, cb, xsb, szb);
    hipLaunchKernelGGL(k4_xdbl, dim3(rows / 64), dim3(256), 0, stream, xsb, xpw, dtg, bcb);
    hipLaunchKernelGGL(k5_scan, dim3(nb * 4), dim3(256), 0, stream,
                       dtg, xsb, szb, bcb, A_log, Dv, dtw, dtb, ysum + (size_t)b0 * DINN);
  }
  hipLaunchKernelGGL(k6_head, dim3(NB), dim3(128), 0, stream,
                     ysum, opw, fc1w, fc1b, fc2w, fc2b, out);
}

// Round 20
// 1390.495 us; speedup vs baseline: 1.0296x; 1.0296x over previous
//
#include <hip/hip_runtime.h>
#include <cstdint>
#include <cstddef>

constexpr int LSEQ = 1000;   // sequence length
constexpr int NB   = 128;    // batch
constexpr int CINP = 12;     // input channels
constexpr int HID  = 128;    // lstm hidden
constexpr int NGATE = 4 * HID;  // 512
constexpr int DMOD = 128;    // d_model
constexpr int DINN = 256;    // d_inner
constexpr int NCL  = 5;

typedef unsigned short ushort_t;
typedef _Float16 half2_t __attribute__((ext_vector_type(2)));
typedef _Float16 half8_t __attribute__((ext_vector_type(8)));
typedef float f32x4 __attribute__((ext_vector_type(4)));

__device__ __forceinline__ float bf2f(ushort_t u) {
  uint32_t b = ((uint32_t)u) << 16;
  float f; __builtin_memcpy(&f, &b, 4); return f;
}
__device__ __forceinline__ ushort_t f2bf(float f) {
  uint32_t b; __builtin_memcpy(&b, &f, 4);
  uint32_t r = (b + 0x7fffu + ((b >> 16) & 1u)) >> 16;
  return (ushort_t)r;
}
__device__ __forceinline__ half2_t u2h2(uint32_t v) {
  half2_t h; __builtin_memcpy(&h, &v, 4); return h;
}
__device__ __forceinline__ uint32_t h22u(half2_t h) {
  uint32_t v; __builtin_memcpy(&v, &h, 4); return v;
}
__device__ __forceinline__ half8_t u4_to_h8(uint4 v) {
  half8_t h; __builtin_memcpy(&h, &v, 16); return h;
}
// two bf16 packed in u32 -> two f16 packed in u32
__device__ __forceinline__ uint32_t bfpair_to_h2(uint32_t v) {
  half2_t h;
  h.x = (_Float16)bf2f((ushort_t)(v & 0xffff));
  h.y = (_Float16)bf2f((ushort_t)(v >> 16));
  return h22u(h);
}

#if __has_builtin(__builtin_amdgcn_fdot2)
__device__ __forceinline__ float FDOT2(half2_t a, half2_t b, float c) {
  return __builtin_amdgcn_fdot2(a, b, c, false);
}
#else
__device__ __forceinline__ float FDOT2(half2_t a, half2_t b, float c) {
  return c + (float)a.x * (float)b.x + (float)a.y * (float)b.y;
}
#endif

// LDS-only barrier: drains lgkmcnt but NOT vmcnt (global stores keep flowing).
__device__ __forceinline__ void bar_lgkm() {
  asm volatile("s_waitcnt lgkmcnt(0)\n\ts_barrier" ::: "memory");
}

// ---------------------------------------------------------------------------
// K0: fold input_proj into in_proj; emit Weff PRE-PACKED as f16 pairs.
__global__ __launch_bounds__(256) void k0_weff(
    const float* __restrict__ ipw, const float* __restrict__ Wp,
    const float* __restrict__ bp, uint32_t* __restrict__ Weffh,
    float* __restrict__ beff) {
  int idx = blockIdx.x * 256 + threadIdx.x;   // grid 128 blocks -> 32768
  if (idx < NGATE * 64) {
    int e = idx >> 6, j = idx & 63;
    float a0 = 0.f, a1 = 0.f;
    for (int d = 0; d < DMOD; ++d) {
      float w = ipw[e * DMOD + d];
      a0 += w * Wp[d * HID + 2 * j];
      a1 += w * Wp[d * HID + 2 * j + 1];
    }
    half2_t h; h.x = (_Float16)a0; h.y = (_Float16)a1;
    Weffh[idx] = h22u(h);
  }
  if (idx < NGATE) {
    float acc = 0.f;
    for (int d = 0; d < DMOD; ++d) acc += ipw[idx * DMOD + d] * bp[d];
    beff[idx] = acc;
  }
}

// ---------------------------------------------------------------------------
// K1: LSTM "split-gate" (FROZEN; best measured: 748 us).
__global__ __launch_bounds__(256, 1) void k1_lstm(
    const float* __restrict__ x, const float* __restrict__ W_ih,
    const float* __restrict__ W_hh, const float* __restrict__ b_ih,
    const float* __restrict__ b_hh, ushort_t* __restrict__ hout) {
  __shared__ __align__(16) float x_sh[LSEQ * CINP];      // 48 KB
  __shared__ __align__(16) ushort_t h_sh[HID];           // f16 bits
  __shared__ float tg_sh[HID];                           // tanh(g) from half1
  __shared__ float so_sh[HID];                           // sig(o)  from half1
  const int t = threadIdx.x;          // 0..255
  const int u = t & 127;              // unit
  const int half = t >> 7;            // 0: rows {u,u+128}; 1: {u+256,u+384}
  const int rA = u + half * 256;      // i or g
  const int rB = rA + 128;            // f or o
  const int b = blockIdx.x;

  const float4* xg4 = reinterpret_cast<const float4*>(x + (size_t)b * LSEQ * CINP);
  float4* xs4 = reinterpret_cast<float4*>(x_sh);
  for (int i = t; i < LSEQ * CINP / 4; i += 256) xs4[i] = xg4[i];

  half2_t wa2[64], wb2[64];
  {
    const float4* wa4 = reinterpret_cast<const float4*>(W_hh) + rA * (HID / 4);
    const float4* wb4 = reinterpret_cast<const float4*>(W_hh) + rB * (HID / 4);
#pragma unroll
    for (int k = 0; k < HID / 4; ++k) {
      float4 v = wa4[k];
      half2_t a; a.x = (_Float16)v.x; a.y = (_Float16)v.y;
      half2_t c; c.x = (_Float16)v.z; c.y = (_Float16)v.w;
      wa2[2 * k] = a; wa2[2 * k + 1] = c;
      float4 w = wb4[k];
      half2_t d; d.x = (_Float16)w.x; d.y = (_Float16)w.y;
      half2_t e; e.x = (_Float16)w.z; e.y = (_Float16)w.w;
      wb2[2 * k] = d; wb2[2 * k + 1] = e;
    }
  }
  float wia[CINP], wib[CINP];
#pragma unroll
  for (int c = 0; c < CINP; ++c) {
    wia[c] = W_ih[rA * CINP + c];
    wib[c] = W_ih[rB * CINP + c];
  }
  const float biasA = b_ih[rA] + b_hh[rA];
  const float biasB = b_ih[rB] + b_hh[rB];

  float cstate = 0.f;
  if (t < HID) h_sh[t] = 0;
  __syncthreads();

  for (int l = 0; l < LSEQ; ++l) {
    const float* xr = &x_sh[l * CINP];
    float pa0 = biasA, pa1 = 0.f, pa2 = 0.f, pa3 = 0.f;
    float pb0 = biasB, pb1 = 0.f, pb2 = 0.f, pb3 = 0.f;
#pragma unroll
    for (int c = 0; c < CINP; c += 4) {
      float x0 = xr[c], x1 = xr[c + 1], x2 = xr[c + 2], x3 = xr[c + 3];
      pa0 += x0 * wia[c];     pa1 += x1 * wia[c + 1];
      pa2 += x2 * wia[c + 2]; pa3 += x3 * wia[c + 3];
      pb0 += x0 * wib[c];     pb1 += x1 * wib[c + 1];
      pb2 += x2 * wib[c + 2]; pb3 += x3 * wib[c + 3];
    }
    const uint4* h4 = reinterpret_cast<const uint4*>(h_sh);
#pragma unroll
    for (int kk = 0; kk < 16; ++kk) {
      uint4 hv = h4[kk];
      half2_t h0 = u2h2(hv.x), h1 = u2h2(hv.y), h2 = u2h2(hv.z), h3 = u2h2(hv.w);
      pa0 = FDOT2(h0, wa2[4 * kk],     pa0);
      pa1 = FDOT2(h1, wa2[4 * kk + 1], pa1);
      pa2 = FDOT2(h2, wa2[4 * kk + 2], pa2);
      pa3 = FDOT2(h3, wa2[4 * kk + 3], pa3);
      pb0 = FDOT2(h0, wb2[4 * kk],     pb0);
      pb1 = FDOT2(h1, wb2[4 * kk + 1], pb1);
      pb2 = FDOT2(h2, wb2[4 * kk + 2], pb2);
      pb3 = FDOT2(h3, wb2[4 * kk + 3], pb3);
    }
    float gA = (pa0 + pa1) + (pa2 + pa3);
    float gB = (pb0 + pb1) + (pb2 + pb3);

    float si = 0.f, sf = 0.f;
    if (half) {
      float tg = 1.f - 2.f / (__expf(2.f * gA) + 1.f);
      float so = 1.f / (1.f + __expf(-gB));
      tg_sh[u] = tg;
      so_sh[u] = so;
    } else {
      si = 1.f / (1.f + __expf(-gA));
      sf = 1.f / (1.f + __expf(-gB));
    }
    bar_lgkm();
    if (!half) {
      cstate = sf * cstate + si * tg_sh[u];
      float th = 1.f - 2.f / (__expf(2.f * cstate) + 1.f);
      float hv = so_sh[u] * th;
      _Float16 hh = (_Float16)hv;
      ushort_t hb; __builtin_memcpy(&hb, &hh, 2);
      h_sh[u] = hb;
      hout[((size_t)b * LSEQ + l) * HID + u] = f2bf(hv);
    }
    bar_lgkm();
  }
}

// ---------------------------------------------------------------------------
// K2f: xz = h @ Weff.T + beff via MFMA (16x16x32 f16), FUSED with causal
//      conv+silu. (verified R17/R18 configuration)
__global__ __launch_bounds__(256) void k2f(
    const ushort_t* __restrict__ hbuf, const uint32_t* __restrict__ Weffh,
    const float* __restrict__ beff, const float* __restrict__ cw,
    const float* __restrict__ cb, ushort_t* __restrict__ xs,
    ushort_t* __restrict__ sz) {
  constexpr int S = 66;                        // u32 stride per 64-pair row
  __shared__ __align__(16) uint32_t smem[2 * 64 * S];   // 33,792 B
  uint32_t* As = smem;
  uint32_t* Bs = smem + 64 * S;
  const int tid = threadIdx.x;
  const size_t m0 = (size_t)blockIdx.x * 64;
  const int n0 = blockIdx.y * 64;

  const uint4* h4g = reinterpret_cast<const uint4*>(hbuf);
  for (int i = tid; i < 64 * 16; i += 256) {
    int row = i >> 4, c = i & 15;
    uint4 v = h4g[(m0 + row) * 16 + c];
    uint32_t* p = &As[row * S + c * 4];
    p[0] = bfpair_to_h2(v.x); p[1] = bfpair_to_h2(v.y);
    p[2] = bfpair_to_h2(v.z); p[3] = bfpair_to_h2(v.w);
  }
  const uint4* w4g = reinterpret_cast<const uint4*>(Weffh);
  for (int i = tid; i < 64 * 16; i += 256) {
    int row = i >> 4, c = i & 15;
    uint4 v = w4g[(size_t)(n0 + row) * 16 + c];
    uint32_t* p = &Bs[row * S + c * 4];
    p[0] = v.x; p[1] = v.y; p[2] = v.z; p[3] = v.w;
  }
  __syncthreads();

  const int w  = tid >> 6;        // wave id -> row-tile
  const int ln = tid & 63;
  const int mr = ln & 15;         // M (A) / N (B) index within tile
  const int g4 = (ln >> 4) * 4;   // kpair offset of this lane group

  uint4 af[4];
#pragma unroll
  for (int kb = 0; kb < 4; ++kb)
    af[kb] = *reinterpret_cast<const uint4*>(&As[(w * 16 + mr) * S + kb * 16 + g4]);

  f32x4 acc[4];
#pragma unroll
  for (int tn = 0; tn < 4; ++tn) {
    f32x4 a = {0.f, 0.f, 0.f, 0.f};
#pragma unroll
    for (int kb = 0; kb < 4; ++kb) {
      uint4 bf = *reinterpret_cast<const uint4*>(&Bs[(tn * 16 + mr) * S + kb * 16 + g4]);
      a = __builtin_amdgcn_mfma_f32_16x16x32_f16(u4_to_h8(af[kb]), u4_to_h8(bf), a, 0, 0, 0);
    }
    acc[tn] = a;
  }

  const int rbase = w * 16 + (ln >> 4) * 4;   // row within 64-row tile

  if (n0 >= 256) {
    // z path: silu -> sz
#pragma unroll
    for (int tn = 0; tn < 4; ++tn) {
      int c = n0 + tn * 16 + mr;
      float bev = beff[c];
#pragma unroll
      for (int r = 0; r < 4; ++r) {
        size_t row = m0 + rbase + r;
        float v = acc[tn][r] + bev;
        sz[row * 256 + (c - 256)] = f2bf(v / (1.f + __expf(-v)));
      }
    }
    return;
  }

  // xi path: 3-row halo xz (rows m0-3..m0-1), masked at batch starts
  float haloval = 0.f;
  const int hc = tid & 63;
  if (tid < 192) {
    int hr = tid >> 6;
    long hrow = (long)m0 - 3 + hr;
    if (hrow < 0) hrow = 0;        // values masked by l-check below
    const uint4* hg = reinterpret_cast<const uint4*>(hbuf + (size_t)hrow * 128);
    const uint32_t* brow = &Bs[hc * S];
    float a0 = beff[n0 + hc], a1 = 0.f, a2 = 0.f, a3 = 0.f;
#pragma unroll
    for (int k = 0; k < 16; ++k) {
      uint4 hv = hg[k];
      a0 = FDOT2(u2h2(bfpair_to_h2(hv.x)), u2h2(brow[4 * k]),     a0);
      a1 = FDOT2(u2h2(bfpair_to_h2(hv.y)), u2h2(brow[4 * k + 1]), a1);
      a2 = FDOT2(u2h2(bfpair_to_h2(hv.z)), u2h2(brow[4 * k + 2]), a2);
      a3 = FDOT2(u2h2(bfpair_to_h2(hv.w)), u2h2(brow[4 * k + 3]), a3);
    }
    haloval = (a0 + a1) + (a2 + a3);
  }
  __syncthreads();   // As/Bs reads complete -> safe to overlay

  float* X = reinterpret_cast<float*>(smem);   // [67][68] fp32 xz tile
#pragma unroll
  for (int tn = 0; tn < 4; ++tn) {
    int c = tn * 16 + mr;
    float bev = beff[n0 + c];
#pragma unroll
    for (int r = 0; r < 4; ++r) {
      X[(rbase + r + 3) * 68 + c] = acc[tn][r] + bev;
    }
  }
  if (tid < 192) X[(tid >> 6) * 68 + hc] = haloval;
  __syncthreads();

  // conv (l-masked) + silu -> xs  (re-reads X with the ty/tx mapping)
  const int tx = tid & 15, ty = tid >> 4;
  const int col = n0 + tx * 4;
  float cw0[4], cw1[4], cw2[4], cw3[4], cbv[4];
#pragma unroll
  for (int j = 0; j < 4; ++j) {
    int d = col + j;
    cw0[j] = cw[d * 4]; cw1[j] = cw[d * 4 + 1];
    cw2[j] = cw[d * 4 + 2]; cw3[j] = cw[d * 4 + 3];
    cbv[j] = cb[d];
  }
#pragma unroll
  for (int i = 0; i < 4; ++i) {
    int r = ty * 4 + i;
    size_t m = m0 + r;
    int l = (int)(m % LSEQ);
    const float* xr3 = &X[(r + 3) * 68 + tx * 4];  // current row
    ushort_t ov[4];
#pragma unroll
    for (int j = 0; j < 4; ++j) {
      float o0 = cbv[j];
      o0 += cw3[j] * xr3[j];
      if (l >= 1) o0 += cw2[j] * xr3[j - 68];
      if (l >= 2) o0 += cw1[j] * xr3[j - 136];
      if (l >= 3) o0 += cw0[j] * xr3[j - 204];
      ov[j] = f2bf(o0 / (1.f + __expf(-o0)));
    }
    ushort4 o; o.x = ov[0]; o.y = ov[1]; o.z = ov[2]; o.w = ov[3];
    *reinterpret_cast<ushort4*>(&xs[m * 256 + col]) = o;
  }
}

// ---------------------------------------------------------------------------
// K4: x_dbl = xs @ x_proj_w.T via MFMA (verified R18).
__global__ __launch_bounds__(256) void k4_xdbl(
    const ushort_t* __restrict__ xs, const float* __restrict__ xpw,
    float* __restrict__ dtg, float* __restrict__ bc) {
  constexpr int S = 130;                       // u32 stride per 128-pair row
  __shared__ __align__(16) uint32_t xsh[64 * S];   // 33.3 KB
  __shared__ __align__(16) uint32_t wsh[48 * S];   // 25.0 KB
  const int tid = threadIdx.x;
  const size_t r0 = (size_t)blockIdx.x * 64;

  const uint4* x4g = reinterpret_cast<const uint4*>(xs);
  for (int i = tid; i < 64 * 32; i += 256) {
    int row = i >> 5, c = i & 31;
    uint4 v = x4g[(r0 + row) * 32 + c];
    uint32_t* p = &xsh[row * S + c * 4];
    p[0] = bfpair_to_h2(v.x); p[1] = bfpair_to_h2(v.y);
    p[2] = bfpair_to_h2(v.z); p[3] = bfpair_to_h2(v.w);
  }
  for (int i = tid; i < 40 * 128; i += 256) {
    int c = i >> 7, kk = i & 127;
    half2_t h;
    h.x = (_Float16)xpw[c * 256 + 2 * kk];
    h.y = (_Float16)xpw[c * 256 + 2 * kk + 1];
    wsh[c * S + kk] = h22u(h);
  }
  for (int i = tid; i < 8 * 128; i += 256) {
    int c = 40 + (i >> 7), kk = i & 127;
    wsh[c * S + kk] = 0u;
  }
  __syncthreads();

  const int w  = tid >> 6;        // wave id -> 16-row tile
  const int ln = tid & 63;
  const int mr = ln & 15;
  const int g4 = (ln >> 4) * 4;

  uint4 af[8];
#pragma unroll
  for (int kb = 0; kb < 8; ++kb)
    af[kb] = *reinterpret_cast<const uint4*>(&xsh[(w * 16 + mr) * S + kb * 16 + g4]);

  f32x4 acc[3];
#pragma unroll
  for (int tn = 0; tn < 3; ++tn) {
    f32x4 a = {0.f, 0.f, 0.f, 0.f};
#pragma unroll
    for (int kb = 0; kb < 8; ++kb) {
      uint4 bf = *reinterpret_cast<const uint4*>(&wsh[(tn * 16 + mr) * S + kb * 16 + g4]);
      a = __builtin_amdgcn_mfma_f32_16x16x32_f16(u4_to_h8(af[kb]), u4_to_h8(bf), a, 0, 0, 0);
    }
    acc[tn] = a;
  }

  const int rbase = w * 16 + (ln >> 4) * 4;
#pragma unroll
  for (int tn = 0; tn < 3; ++tn) {
    int c = tn * 16 + mr;
#pragma unroll
    for (int r = 0; r < 4; ++r) {
      size_t row = r0 + rbase + r;
      float v = acc[tn][r];
      if (c < 8) dtg[row * 8 + c] = v;
      else if (c < 40) bc[row * 32 + (c - 8)] = v;
    }
  }
}

// ---------------------------------------------------------------------------
// K5: selective scan (best measured config, R18). 8 threads per (b,d), 2
//     states each; software prefetch of l+1; reduction hoisted out of loop.
__global__ __launch_bounds__(256) void k5_scan(
    const float* __restrict__ dtg, const ushort_t* __restrict__ xs,
    const ushort_t* __restrict__ sz, const float* __restrict__ bc,
    const float* __restrict__ A_log, const float* __restrict__ Dv,
    const float* __restrict__ dtw, const float* __restrict__ dtb,
    float* __restrict__ ysum) {
  const int b  = blockIdx.x >> 3;
  const int d  = ((blockIdx.x & 7) << 5) + (threadIdx.x >> 3);  // 0..255
  const int sg = threadIdx.x & 7;                                // 2 states each

  const float Aa0 = -__expf(A_log[d * 16 + sg * 2]);
  const float Aa1 = -__expf(A_log[d * 16 + sg * 2 + 1]);
  float w8[8];
#pragma unroll
  for (int r = 0; r < 8; ++r) w8[r] = dtw[d * 8 + r];
  const float db = dtb[d];
  const float DD = Dv[d];

  float h0 = 0.f, h1 = 0.f;
  float acc = 0.f, accD = 0.f;
  const size_t base = (size_t)b * LSEQ;

  float4 dta_c = *reinterpret_cast<const float4*>(&dtg[base * 8]);
  float4 dtb_c = *reinterpret_cast<const float4*>(&dtg[base * 8 + 4]);
  float  xv_c  = bf2f(xs[base * 256 + d]);
  float  zv_c  = bf2f(sz[base * 256 + d]);
  float2 bv_c  = *reinterpret_cast<const float2*>(&bc[base * 32 + sg * 2]);
  float2 cv_c  = *reinterpret_cast<const float2*>(&bc[base * 32 + 16 + sg * 2]);

  for (int l = 0; l < LSEQ; ++l) {
    const size_t nrow = base + ((l + 1 < LSEQ) ? (l + 1) : l);
    float4 dta_n = *reinterpret_cast<const float4*>(&dtg[nrow * 8]);
    float4 dtb_n = *reinterpret_cast<const float4*>(&dtg[nrow * 8 + 4]);
    float  xv_n  = bf2f(xs[nrow * 256 + d]);
    float  zv_n  = bf2f(sz[nrow * 256 + d]);
    float2 bv_n  = *reinterpret_cast<const float2*>(&bc[nrow * 32 + sg * 2]);
    float2 cv_n  = *reinterpret_cast<const float2*>(&bc[nrow * 32 + 16 + sg * 2]);

    float a = db + dta_c.x * w8[0] + dta_c.y * w8[1] + dta_c.z * w8[2] + dta_c.w * w8[3]
                 + dtb_c.x * w8[4] + dtb_c.y * w8[5] + dtb_c.z * w8[6] + dtb_c.w * w8[7];
    float dl = (a > 20.f) ? a : __logf(1.f + __expf(a));
    float dx = dl * xv_c;
    h0 = __expf(dl * Aa0) * h0 + dx * bv_c.x;
    h1 = __expf(dl * Aa1) * h1 + dx * bv_c.y;
    acc += (h0 * cv_c.x + h1 * cv_c.y) * zv_c;
    accD += xv_c * zv_c;

    dta_c = dta_n; dtb_c = dtb_n;
    xv_c = xv_n; zv_c = zv_n; bv_c = bv_n; cv_c = cv_n;
  }
  if (sg == 0) acc += DD * accD;
  acc += __shfl_xor(acc, 1);
  acc += __shfl_xor(acc, 2);
  acc += __shfl_xor(acc, 4);
  if (sg == 0) ysum[b * 256 + d] = acc;
}

// ---------------------------------------------------------------------------
// K6: head. pooled = ysum@opw.T/L ; fc1+relu ; fc2.
__global__ __launch_bounds__(128) void k6_head(
    const float* __restrict__ ysum, const float* __restrict__ opw,
    const float* __restrict__ fc1w, const float* __restrict__ fc1b,
    const float* __restrict__ fc2w, const float* __restrict__ fc2b,
    float* __restrict__ out) {
  __shared__ float ys[256], pool[128], fcs[128];
  const int b = blockIdx.x, t = threadIdx.x;
  for (int i = t; i < 256; i += 128) ys[i] = ysum[b * 256 + i];
  __syncthreads();
  float a = 0.f;
  for (int e = 0; e < 256; ++e) a += opw[t * 256 + e] * ys[e];
  pool[t] = a * (1.0f / (float)LSEQ);
  __syncthreads();
  float a1 = fc1b[t];
  for (int d2 = 0; d2 < 128; ++d2) a1 += fc1w[t * 128 + d2] * pool[d2];
  fcs[t] = fmaxf(a1, 0.f);
  __syncthreads();
  if (t < NCL) {
    float o = fc2b[t];
    for (int f = 0; f < 128; ++f) o += fc2w[t * 128 + f] * fcs[f];
    out[b * NCL + t] = o;
  }
}

// ---------------------------------------------------------------------------
extern "C" void kernel_launch(void* const* d_in, const int* in_sizes, int n_in,
                              void* d_out, int out_size, void* d_ws, size_t ws_size,
                              hipStream_t stream) {
  const float* x     = (const float*)d_in[0];
  const float* W_ih  = (const float*)d_in[1];
  const float* W_hh  = (const float*)d_in[2];
  const float* b_ih  = (const float*)d_in[3];
  const float* b_hh  = (const float*)d_in[4];
  const float* Wp    = (const float*)d_in[5];
  const float* bp    = (const float*)d_in[6];
  const float* ipw   = (const float*)d_in[7];
  const float* cw    = (const float*)d_in[8];
  const float* cb    = (const float*)d_in[9];
  const float* xpw   = (const float*)d_in[10];
  const float* dtw   = (const float*)d_in[11];
  const float* dtb   = (const float*)d_in[12];
  const float* A_log = (const float*)d_in[13];
  const float* Dv    = (const float*)d_in[14];
  const float* opw   = (const float*)d_in[15];
  const float* fc1w  = (const float*)d_in[16];
  const float* fc1b  = (const float*)d_in[17];
  const float* fc2w  = (const float*)d_in[18];
  const float* fc2b  = (const float*)d_in[19];
  float* out = (float*)d_out;

  const size_t A_WEFF = 131072;                          // packed f16 pairs
  const size_t A_BEFF = 4096, A_YSUM = 131072;
  const size_t A_HBUF = (size_t)NB * LSEQ * HID * 2;     // 32.77 MB
  const size_t A_XS   = (size_t)NB * LSEQ * DINN * 2;    // 65.54 MB
  const size_t A_SZ   = A_XS;                            // 65.54 MB
  const size_t A_DT   = (size_t)NB * LSEQ * 8 * 4;       // 4.10 MB
  const size_t A_BC   = (size_t)NB * LSEQ * 32 * 4;      // 16.38 MB
  const size_t FIXED_WIDE = A_WEFF + A_BEFF + A_YSUM + A_HBUF + A_XS + A_SZ + A_DT + A_BC;
  // FIXED_WIDE = 184.6 MB (no xi buffer)

  if (FIXED_WIDE <= ws_size) {
    char* p = (char*)d_ws;
    uint32_t* Weffh = (uint32_t*)p; p += A_WEFF;
    float*    beff = (float*)p;    p += A_BEFF;
    float*    ysum = (float*)p;    p += A_YSUM;
    ushort_t* hbuf = (ushort_t*)p; p += A_HBUF;
    ushort_t* xsb  = (ushort_t*)p; p += A_XS;
    ushort_t* szb  = (ushort_t*)p; p += A_SZ;
    float*    dtg  = (float*)p;    p += A_DT;
    float*    bcb  = (float*)p;    p += A_BC;

    const int rows = NB * LSEQ;      // 128000
    hipLaunchKernelGGL(k0_weff, dim3(128), dim3(256), 0, stream, ipw, Wp, bp, Weffh, beff);
    hipLaunchKernelGGL(k1_lstm, dim3(NB), dim3(256), 0, stream, x, W_ih, W_hh, b_ih, b_hh, hbuf);
    hipLaunchKernelGGL(k2f, dim3(rows / 64, 8), dim3(256), 0, stream,
                       hbuf, Weffh, beff, cw, cb, xsb, szb);
    hipLaunchKernelGGL(k4_xdbl, dim3(rows / 64), dim3(256), 0, stream,
                       xsb, xpw, dtg, bcb);
    hipLaunchKernelGGL(k5_scan, dim3(NB * 8), dim3(256), 0, stream,
                       dtg, xsb, szb, bcb, A_log, Dv, dtw, dtb, ysum);
    hipLaunchKernelGGL(k6_head, dim3(NB), dim3(128), 0, stream,
                       ysum, opw, fc1w, fc1b, fc2w, fc2b, out);
    return;
  }

  // --- fallback: chunked over batches (same fused kernel; chunks start at
  //     batch boundaries so the conv l-masking stays correct) ---
  const size_t FIXED = A_WEFF + A_BEFF + A_YSUM + A_HBUF;
  const size_t PERB = (size_t)LSEQ * DINN * 2 * 2 + (size_t)LSEQ * 8 * 4 + (size_t)LSEQ * 32 * 4;
  int nb = 8;
  for (int c = 64; c >= 8; c >>= 1) {
    if (FIXED + (size_t)c * PERB <= ws_size) { nb = c; break; }
  }
  char* p = (char*)d_ws;
  uint32_t* Weffh = (uint32_t*)p; p += A_WEFF;
  float*    beff = (float*)p;    p += A_BEFF;
  float*    ysum = (float*)p;    p += A_YSUM;
  ushort_t* hbuf = (ushort_t*)p; p += A_HBUF;
  ushort_t* xsb  = (ushort_t*)p; p += (size_t)nb * LSEQ * DINN * 2;
  ushort_t* szb  = (ushort_t*)p; p += (size_t)nb * LSEQ * DINN * 2;
  float*    dtg  = (float*)p;    p += (size_t)nb * LSEQ * 8 * 4;
  float*    bcb  = (float*)p;

  hipLaunchKernelGGL(k0_weff, dim3(128), dim3(256), 0, stream, ipw, Wp, bp, Weffh, beff);
  hipLaunchKernelGGL(k1_lstm, dim3(NB), dim3(256), 0, stream, x, W_ih, W_hh, b_ih, b_hh, hbuf);
  for (int b0 = 0; b0 < NB; b0 += nb) {
    const int rows = nb * LSEQ;
    hipLaunchKernelGGL(k2f, dim3(rows / 64, 8), dim3(256), 0, stream,
                       hbuf + (size_t)b0 * LSEQ * HID, Weffh, beff, cw, cb, xsb, szb);
    hipLaunchKernelGGL(k4_xdbl, dim3(rows / 64), dim3(256), 0, stream, xsb, xpw, dtg, bcb);
    hipLaunchKernelGGL(k5_scan, dim3(nb * 8), dim3(256), 0, stream,
                       dtg, xsb, szb, bcb, A_log, Dv, dtw, dtb, ysum + (size_t)b0 * DINN);
  }
  hipLaunchKernelGGL(k6_head, dim3(NB), dim3(128), 0, stream,
                     ysum, opw, fc1w, fc1b, fc2w, fc2b, out);
}